// Round 1
// baseline (821.596 us; speedup 1.0000x reference)
//
#include <hip/hip_runtime.h>
#include <math.h>

#define D_MODEL 512
#define D_FF    2048
#define N_EXP   8
#define N_TOK   8192
#define BM      64
#define BF      64

typedef _Float16 half8 __attribute__((ext_vector_type(8)));
typedef float    f32x4 __attribute__((ext_vector_type(4)));

__device__ __forceinline__ void gload_lds16(const void* g, void* lds) {
  __builtin_amdgcn_global_load_lds(
      (const __attribute__((address_space(1))) unsigned int*)g,
      (__attribute__((address_space(3))) unsigned int*)lds, 16, 0, 0);
}

// ---------------- x -> fp16 ----------------
__global__ void cvt_x_kernel(const float* __restrict__ x, _Float16* __restrict__ xb) {
  int i = blockIdx.x * blockDim.x + threadIdx.x;   // 8 elems per thread
  const float4* xp = (const float4*)x + (size_t)i * 2;
  float4 v0 = xp[0], v1 = xp[1];
  half8 o;
  o[0] = (_Float16)v0.x; o[1] = (_Float16)v0.y; o[2] = (_Float16)v0.z; o[3] = (_Float16)v0.w;
  o[4] = (_Float16)v1.x; o[5] = (_Float16)v1.y; o[6] = (_Float16)v1.z; o[7] = (_Float16)v1.w;
  ((half8*)xb)[i] = o;
}

// ---------------- [E][R][C] f32 -> [E][C][R] f16 ----------------
__global__ void transpose_cvt_kernel(const float* __restrict__ in, _Float16* __restrict__ out,
                                     int R, int C) {
  __shared__ float t[32][33];
  int e = blockIdx.z, rb = blockIdx.y, cb = blockIdx.x;
  int tx = threadIdx.x & 31, ty = threadIdx.x >> 5;
  const float* src = in + ((size_t)e * R + rb * 32) * C + cb * 32;
#pragma unroll
  for (int i = 0; i < 32; i += 8) t[ty + i][tx] = src[(size_t)(ty + i) * C + tx];
  __syncthreads();
  _Float16* dst = out + ((size_t)e * C + cb * 32) * R + rb * 32;
#pragma unroll
  for (int i = 0; i < 32; i += 8) dst[(size_t)(ty + i) * R + tx] = (_Float16)t[tx][ty + i];
}

// ---------------- router: softmax(x @ wr + br) ----------------
__global__ void router_kernel(const float* __restrict__ x, const float* __restrict__ wr,
                              const float* __restrict__ br, float* __restrict__ route) {
  int t = (blockIdx.x * blockDim.x + threadIdx.x) >> 6;   // one wave per token
  int lane = threadIdx.x & 63;
  const float4* xp = (const float4*)(x + (size_t)t * D_MODEL) + lane * 2;
  float4 xv0 = xp[0], xv1 = xp[1];
  float xv[8] = {xv0.x, xv0.y, xv0.z, xv0.w, xv1.x, xv1.y, xv1.z, xv1.w};
  float acc[8] = {0, 0, 0, 0, 0, 0, 0, 0};
  int d0 = lane * 8;
#pragma unroll
  for (int i = 0; i < 8; ++i) {
    const float4* wp = (const float4*)(wr + (size_t)(d0 + i) * N_EXP);
    float4 w0 = wp[0], w1v = wp[1];
    acc[0] += xv[i] * w0.x;  acc[1] += xv[i] * w0.y;
    acc[2] += xv[i] * w0.z;  acc[3] += xv[i] * w0.w;
    acc[4] += xv[i] * w1v.x; acc[5] += xv[i] * w1v.y;
    acc[6] += xv[i] * w1v.z; acc[7] += xv[i] * w1v.w;
  }
#pragma unroll
  for (int off = 32; off > 0; off >>= 1)
#pragma unroll
    for (int e2 = 0; e2 < 8; ++e2) acc[e2] += __shfl_xor(acc[e2], off);
  float mx = -1e30f;
#pragma unroll
  for (int e2 = 0; e2 < 8; ++e2) { acc[e2] += br[e2]; mx = fmaxf(mx, acc[e2]); }
  float s = 0.f;
#pragma unroll
  for (int e2 = 0; e2 < 8; ++e2) { acc[e2] = expf(acc[e2] - mx); s += acc[e2]; }
  float inv = 1.f / s;
  if (lane < 8) route[(size_t)t * N_EXP + lane] = acc[lane] * inv;
}

// ---------------- fused MoE main ----------------
// grid (N_TOK/BM, N_EXP), 512 threads (8 waves).
// LDS layouts (all XOR-swizzled: 16B slot ^= row&7 within each 128B group):
//   xs  [64][512] f16  A of gemm1
//   w1s [2][64f][64k]  B of gemm1 (from w1t = [E][F][D])
//   hs  [64][64]  f16  A of gemm2 (route-scaled gelu)
//   w2s [512d][64f]    B of gemm2 (from w2t = [E][D][F])
__global__ __launch_bounds__(512, 2)
void moe_main_kernel(const _Float16* __restrict__ xb, const _Float16* __restrict__ w1t,
                     const _Float16* __restrict__ w2t, const float* __restrict__ b1,
                     const float* __restrict__ b2, const float* __restrict__ route,
                     float* __restrict__ out) {
  __shared__ __align__(16) unsigned char xs[BM * D_MODEL * 2];     // 65536
  __shared__ __align__(16) unsigned char w1s[2][BF * 64 * 2];      // 2*8192
  __shared__ __align__(16) unsigned char hs[BM * BF * 2];          // 8192
  __shared__ __align__(16) unsigned char w2s[D_MODEL * BF * 2];    // 65536
  __shared__ float routes_lds[BM];

  const int tid  = threadIdx.x;
  const int lane = tid & 63;
  const int w    = tid >> 6;
  const int e    = blockIdx.y;
  const int m0   = blockIdx.x * BM;

  if (tid < BM) routes_lds[tid] = route[(size_t)(m0 + tid) * N_EXP + e];

  // stage x tile once: 64 rows x 1024B, pre-swizzled source (rule #21)
#pragma unroll
  for (int i = 0; i < 8; ++i) {
    int r = i * 8 + w;
    int srcslot = (lane & ~7) | ((lane ^ r) & 7);
    gload_lds16((const char*)xb + ((size_t)(m0 + r) * D_MODEL + srcslot * 8) * 2,
                xs + r * 1024);
  }

  f32x4 acc[2][8];
#pragma unroll
  for (int mi = 0; mi < 2; ++mi)
#pragma unroll
    for (int jn = 0; jn < 8; ++jn) acc[mi][jn] = (f32x4){0.f, 0.f, 0.f, 0.f};

  f32x4 hacc[2];
  hacc[0] = (f32x4){0.f, 0.f, 0.f, 0.f};
  hacc[1] = (f32x4){0.f, 0.f, 0.f, 0.f};

  const int am1   = 16 * (w >> 1) + (lane & 15);  // gemm1 A row (wave m-frag)
  const int fband = 32 * (w & 1);                 // gemm1 B col band

  for (int fc = 0; fc < D_FF / BF; ++fc) {
    const int f0 = fc * BF;

    { // stage w1 k-step 0 into buf 0 (each wave: 8 rows x 128B)
      int fr = 8 * w + (lane >> 3);
      int sl = (lane & 7) ^ (fr & 7);
      gload_lds16((const char*)w1t + (((size_t)e * D_FF + f0 + fr) * D_MODEL + sl * 8) * 2,
                  w1s[0] + w * 1024);
    }
    __syncthreads();

    // ---- GEMM1: h[64,64] = x[64,512] @ w1t[f0:f0+64, :]^T, double-buffered ----
#pragma unroll
    for (int ks = 0; ks < 8; ++ks) {
      if (ks < 7) {
        int k0n = (ks + 1) * 64;
        int fr = 8 * w + (lane >> 3);
        int sl = (lane & 7) ^ (fr & 7);
        gload_lds16((const char*)w1t + (((size_t)e * D_FF + f0 + fr) * D_MODEL + k0n + sl * 8) * 2,
                    w1s[(ks + 1) & 1] + w * 1024);
      }
      const unsigned char* wbuf = w1s[ks & 1];
#pragma unroll
      for (int kh = 0; kh < 2; ++kh) {
        int kk  = ks * 64 + kh * 32;
        int asl = (kk >> 3) + (lane >> 4);
        int asp = (asl & ~7) | ((asl ^ am1) & 7);
        half8 a = *(const half8*)(xs + am1 * 1024 + asp * 16);
#pragma unroll
        for (int j = 0; j < 2; ++j) {
          int bf_ = fband + 16 * j + (lane & 15);
          int bsp = (kh * 4 + (lane >> 4)) ^ (bf_ & 7);
          half8 b = *(const half8*)(wbuf + bf_ * 128 + bsp * 16);
          hacc[j] = __builtin_amdgcn_mfma_f32_16x16x32_f16(a, b, hacc[j], 0, 0, 0);
        }
      }
      __syncthreads();
    }

    // ---- bias + exact gelu + route-scale, write hs ----
#pragma unroll
    for (int j = 0; j < 2; ++j) {
      int flocal = fband + 16 * j + (lane & 15);
      float b1v = b1[(size_t)e * D_FF + f0 + flocal];
#pragma unroll
      for (int r = 0; r < 4; ++r) {
        int m = 16 * (w >> 1) + (lane >> 4) * 4 + r;   // D-layout: col=lane&15, row=(lane>>4)*4+r
        float v = hacc[j][r] + b1v;
        float g = 0.5f * v * (1.0f + erff(v * 0.70710678118654752f));
        g *= routes_lds[m];
        int sp = (flocal >> 3) ^ (m & 7);
        *(_Float16*)(hs + m * 128 + sp * 16 + (flocal & 7) * 2) = (_Float16)g;
      }
      hacc[j] = (f32x4){0.f, 0.f, 0.f, 0.f};
    }
    // stage w2 chunk [512d][64f] (64KB, 8 issues/thread)
#pragma unroll
    for (int i = 0; i < 8; ++i) {
      int jrow = i * 8 + w;
      int dr = 8 * jrow + (lane >> 3);
      int sl = (lane & 7) ^ (dr & 7);
      gload_lds16((const char*)w2t + (((size_t)e * D_MODEL + dr) * D_FF + f0 + sl * 8) * 2,
                  w2s + jrow * 1024);
    }
    __syncthreads();

    // ---- GEMM2: out[64,512] += hs[64,64] @ w2t[:, f0:f0+64]^T ----
#pragma unroll
    for (int ksx = 0; ksx < 2; ++ksx) {
      half8 a2[2];
#pragma unroll
      for (int mi = 0; mi < 2; ++mi) {
        int am2 = 32 * (w >> 2) + 16 * mi + (lane & 15);
        int sp = (ksx * 4 + (lane >> 4)) ^ (am2 & 7);
        a2[mi] = *(const half8*)(hs + am2 * 128 + sp * 16);
      }
#pragma unroll
      for (int jn = 0; jn < 8; ++jn) {
        int dcol = 128 * (w & 3) + 16 * jn + (lane & 15);
        int sp = (ksx * 4 + (lane >> 4)) ^ (dcol & 7);
        half8 b = *(const half8*)(w2s + dcol * 128 + sp * 16);
        acc[0][jn] = __builtin_amdgcn_mfma_f32_16x16x32_f16(a2[0], b, acc[0][jn], 0, 0, 0);
        acc[1][jn] = __builtin_amdgcn_mfma_f32_16x16x32_f16(a2[1], b, acc[1][jn], 0, 0, 0);
      }
    }
    // no barrier: next iter's w1s[0] stage touches only w1s; first barrier there covers.
  }

  // ---- epilogue: += route*b2, atomic-accumulate across experts ----
#pragma unroll
  for (int mi = 0; mi < 2; ++mi)
#pragma unroll
    for (int jn = 0; jn < 8; ++jn) {
      int dcol = 128 * (w & 3) + 16 * jn + (lane & 15);
      float b2v = b2[(size_t)e * D_MODEL + dcol];
#pragma unroll
      for (int r = 0; r < 4; ++r) {
        int m = 32 * (w >> 2) + 16 * mi + (lane >> 4) * 4 + r;
        float val = acc[mi][jn][r] + routes_lds[m] * b2v;
        unsafeAtomicAdd(out + (size_t)(m0 + m) * D_MODEL + dcol, val);
      }
    }
}

extern "C" void kernel_launch(void* const* d_in, const int* in_sizes, int n_in,
                              void* d_out, int out_size, void* d_ws, size_t ws_size,
                              hipStream_t stream) {
  (void)in_sizes; (void)n_in; (void)out_size; (void)ws_size;
  const float* x  = (const float*)d_in[0];
  const float* w1 = (const float*)d_in[1];
  const float* b1 = (const float*)d_in[2];
  const float* w2 = (const float*)d_in[3];
  const float* b2 = (const float*)d_in[4];
  const float* wr = (const float*)d_in[5];
  const float* br = (const float*)d_in[6];
  float* out   = (float*)d_out;
  float* route = out + (size_t)N_TOK * D_MODEL;   // output 1 lives in d_out tail

  char* ws = (char*)d_ws;
  _Float16* xb  = (_Float16*)ws;                                           // 8 MiB
  _Float16* w1t = (_Float16*)(ws + (size_t)N_TOK * D_MODEL * 2);           // +16 MiB  [E][F][D]
  _Float16* w2t = (_Float16*)(ws + (size_t)N_TOK * D_MODEL * 2
                                 + (size_t)N_EXP * D_FF * D_MODEL * 2);    // +16 MiB  [E][D][F]

  hipMemsetAsync(out, 0, (size_t)N_TOK * D_MODEL * sizeof(float), stream);
  cvt_x_kernel<<<(N_TOK * D_MODEL / 8) / 256, 256, 0, stream>>>(x, xb);
  transpose_cvt_kernel<<<dim3(D_FF / 32, D_MODEL / 32, N_EXP), 256, 0, stream>>>(w1, w1t, D_MODEL, D_FF);
  transpose_cvt_kernel<<<dim3(D_MODEL / 32, D_FF / 32, N_EXP), 256, 0, stream>>>(w2, w2t, D_FF, D_MODEL);
  router_kernel<<<N_TOK / 4, 256, 0, stream>>>(x, wr, br, route);
  moe_main_kernel<<<dim3(N_TOK / BM, N_EXP), 512, 0, stream>>>(xb, w1t, w2t, b1, b2, route, out);
}

// Round 2
// 638.383 us; speedup vs baseline: 1.2870x; 1.2870x over previous
//
#include <hip/hip_runtime.h>
#include <math.h>

#define D_MODEL 512
#define D_FF    2048
#define N_EXP   8
#define N_TOK   8192
#define BM      64
#define BF      64

typedef _Float16 half8 __attribute__((ext_vector_type(8)));
typedef float    f32x4 __attribute__((ext_vector_type(4)));

__device__ __forceinline__ void gload_lds16(const void* g, void* lds) {
  __builtin_amdgcn_global_load_lds(
      (const __attribute__((address_space(1))) unsigned int*)g,
      (__attribute__((address_space(3))) unsigned int*)lds, 16, 0, 0);
}

// ---------------- x -> fp16 ----------------
__global__ void cvt_x_kernel(const float* __restrict__ x, _Float16* __restrict__ xb) {
  int i = blockIdx.x * blockDim.x + threadIdx.x;   // 8 elems per thread
  const float4* xp = (const float4*)x + (size_t)i * 2;
  float4 v0 = xp[0], v1 = xp[1];
  half8 o;
  o[0] = (_Float16)v0.x; o[1] = (_Float16)v0.y; o[2] = (_Float16)v0.z; o[3] = (_Float16)v0.w;
  o[4] = (_Float16)v1.x; o[5] = (_Float16)v1.y; o[6] = (_Float16)v1.z; o[7] = (_Float16)v1.w;
  ((half8*)xb)[i] = o;
}

// ---------------- [E][R][C] f32 -> [E][C][R] f16 ----------------
__global__ void transpose_cvt_kernel(const float* __restrict__ in, _Float16* __restrict__ out,
                                     int R, int C) {
  __shared__ float t[32][33];
  int e = blockIdx.z, rb = blockIdx.y, cb = blockIdx.x;
  int tx = threadIdx.x & 31, ty = threadIdx.x >> 5;
  const float* src = in + ((size_t)e * R + rb * 32) * C + cb * 32;
#pragma unroll
  for (int i = 0; i < 32; i += 8) t[ty + i][tx] = src[(size_t)(ty + i) * C + tx];
  __syncthreads();
  _Float16* dst = out + ((size_t)e * C + cb * 32) * R + rb * 32;
#pragma unroll
  for (int i = 0; i < 32; i += 8) dst[(size_t)(ty + i) * R + tx] = (_Float16)t[tx][ty + i];
}

// ---------------- router: softmax(x @ wr + br) ----------------
__global__ void router_kernel(const float* __restrict__ x, const float* __restrict__ wr,
                              const float* __restrict__ br, float* __restrict__ route) {
  int t = (blockIdx.x * blockDim.x + threadIdx.x) >> 6;   // one wave per token
  int lane = threadIdx.x & 63;
  const float4* xp = (const float4*)(x + (size_t)t * D_MODEL) + lane * 2;
  float4 xv0 = xp[0], xv1 = xp[1];
  float xv[8] = {xv0.x, xv0.y, xv0.z, xv0.w, xv1.x, xv1.y, xv1.z, xv1.w};
  float acc[8] = {0, 0, 0, 0, 0, 0, 0, 0};
  int d0 = lane * 8;
#pragma unroll
  for (int i = 0; i < 8; ++i) {
    const float4* wp = (const float4*)(wr + (size_t)(d0 + i) * N_EXP);
    float4 w0 = wp[0], w1v = wp[1];
    acc[0] += xv[i] * w0.x;  acc[1] += xv[i] * w0.y;
    acc[2] += xv[i] * w0.z;  acc[3] += xv[i] * w0.w;
    acc[4] += xv[i] * w1v.x; acc[5] += xv[i] * w1v.y;
    acc[6] += xv[i] * w1v.z; acc[7] += xv[i] * w1v.w;
  }
#pragma unroll
  for (int off = 32; off > 0; off >>= 1)
#pragma unroll
    for (int e2 = 0; e2 < 8; ++e2) acc[e2] += __shfl_xor(acc[e2], off);
  float mx = -1e30f;
#pragma unroll
  for (int e2 = 0; e2 < 8; ++e2) { acc[e2] += br[e2]; mx = fmaxf(mx, acc[e2]); }
  float s = 0.f;
#pragma unroll
  for (int e2 = 0; e2 < 8; ++e2) { acc[e2] = expf(acc[e2] - mx); s += acc[e2]; }
  float inv = 1.f / s;
  if (lane < 8) route[(size_t)t * N_EXP + lane] = acc[lane] * inv;
}

// ---------------- staging: one 16KB chunk of the per-fc stream ----------------
// idx 0..3: w1 chunk [64f][128k] (k8 = idx);  idx 4..7: w2 chunk [128d][64f] (c = idx-4).
// All LDS writes linear (global_load_lds), source pre-swizzled (XOR involution, rule #21).
__device__ __forceinline__ void stage_chunk(const _Float16* __restrict__ w1t,
                                            const _Float16* __restrict__ w2t,
                                            int e, int f0, int idx, void* slot,
                                            int w, int l) {
  if (idx < 4) {
    const int k0 = idx * 128;
#pragma unroll
    for (int i = 0; i < 2; ++i) {
      int fr = i * 32 + w * 4 + (l >> 4);           // row (f) 0..63
      int s  = l & 15;                               // 16B slot 0..15 (256B row)
      int sw = (s & 8) | ((s ^ (fr & 7)) & 7);
      gload_lds16(w1t + ((size_t)e * D_FF + f0 + fr) * D_MODEL + k0 + sw * 8,
                  (char*)slot + (i * 32 + w * 4) * 256);
    }
  } else {
    const int d0 = (idx - 4) * 128;
#pragma unroll
    for (int i = 0; i < 2; ++i) {
      int dr = i * 64 + w * 8 + (l >> 3);           // row (d) 0..127
      int s  = l & 7;                                // 16B slot 0..7 (128B row)
      int sw = s ^ (dr & 7);
      gload_lds16(w2t + ((size_t)e * D_MODEL + d0 + dr) * D_FF + f0 + sw * 8,
                  (char*)slot + (i * 64 + w * 8) * 128);
    }
  }
}

// ---------------- fused MoE main ----------------
// grid (N_TOK/BM, N_EXP), 512 threads (8 waves), 1 block/CU (74KB LDS, ~180 VGPR).
// Counted-vmcnt chunk pipeline (T4): 4-slot ring, stage 3 ahead, vmcnt(4)+s_barrier
// per chunk, NEVER vmcnt(0) in the loop. x A-fragments live in registers.
__global__ __launch_bounds__(512, 2)
void moe_main_kernel(const _Float16* __restrict__ xb, const _Float16* __restrict__ w1t,
                     const _Float16* __restrict__ w2t, const float* __restrict__ b1,
                     const float* __restrict__ b2, const float* __restrict__ route,
                     float* __restrict__ out) {
  __shared__ __align__(16) unsigned char ring[4][16384];   // 64 KB chunk ring
  __shared__ __align__(16) unsigned char hs[BM * BF * 2];  // 8 KB, row=128B, XOR-swizzled
  __shared__ float routes_lds[BM];

  const int tid = threadIdx.x;
  const int l   = tid & 63;
  const int w   = tid >> 6;
  const int e   = blockIdx.y;
  const int m0  = blockIdx.x * BM;

  const int mh1 = w >> 1, fh1 = w & 1;   // GEMM1: m 4-way x f 2-way
  const int mh2 = w >> 2, dq  = w & 3;   // GEMM2: m 2-way x d 4-way (32-col stripes/chunk)

  if (tid < BM) routes_lds[tid] = route[(size_t)(m0 + tid) * N_EXP + e];

  // x A-fragments in registers: rows m0 + 16*mh1 + (l&15), all 16 k-steps of K=512
  half8 xfrag[16];
  {
    const _Float16* xrow = xb + (size_t)(m0 + 16 * mh1 + (l & 15)) * D_MODEL + ((l >> 4) * 8);
#pragma unroll
    for (int ks = 0; ks < 16; ++ks)
      xfrag[ks] = *(const half8*)(xrow + ks * 32);
  }

  // prologue: stage chunks 0,1,2 of fc 0 (w1 k8=0..2)
  stage_chunk(w1t, w2t, e, 0, 0, ring[0], w, l);
  stage_chunk(w1t, w2t, e, 0, 1, ring[1], w, l);
  stage_chunk(w1t, w2t, e, 0, 2, ring[2], w, l);
  asm volatile("s_waitcnt lgkmcnt(0)" ::: "memory");  // routes_lds visible after 1st barrier

  f32x4 acc[2][8];
#pragma unroll
  for (int mi = 0; mi < 2; ++mi)
#pragma unroll
    for (int jn = 0; jn < 8; ++jn) acc[mi][jn] = (f32x4){0.f, 0.f, 0.f, 0.f};

#pragma unroll 1
  for (int fc = 0; fc < 32; ++fc) {
    const int f0  = fc * BF;
    const int f0n = ((fc + 1) & 31) * BF;

    f32x4 hacc[2];
    hacc[0] = (f32x4){0.f, 0.f, 0.f, 0.f};
    hacc[1] = (f32x4){0.f, 0.f, 0.f, 0.f};

    // ---- GEMM1: chunks 0..3 (w1 [64f][128k]) ----
#pragma unroll
    for (int k8 = 0; k8 < 4; ++k8) {
      asm volatile("s_waitcnt vmcnt(4)" ::: "memory");   // chunk k8 landed (2 chunks in flight)
      __builtin_amdgcn_s_barrier();
      const unsigned char* bb = ring[k8 & 3];
      __builtin_amdgcn_s_setprio(1);
#pragma unroll
      for (int kh = 0; kh < 4; ++kh) {
#pragma unroll
        for (int j = 0; j < 2; ++j) {
          const int bf_ = 32 * fh1 + 16 * j + (l & 15);
          const int g   = kh * 4 + (l >> 4);
          const int sw  = (g & 8) | ((g ^ (bf_ & 7)) & 7);
          half8 b = *(const half8*)(bb + bf_ * 256 + sw * 16);
          hacc[j] = __builtin_amdgcn_mfma_f32_16x16x32_f16(xfrag[k8 * 4 + kh], b, hacc[j], 0, 0, 0);
        }
      }
      __builtin_amdgcn_s_setprio(0);
      const int j2 = k8 + 3;                              // stage 3 ahead: chunks 3..6
      stage_chunk(w1t, w2t, e, f0, j2, ring[j2 & 3], w, l);
    }

    // ---- bias + exact gelu + route-scale -> hs ----
#pragma unroll
    for (int j = 0; j < 2; ++j) {
      const int flocal = 32 * fh1 + 16 * j + (l & 15);
      float b1v = b1[(size_t)e * D_FF + f0 + flocal];
#pragma unroll
      for (int r = 0; r < 4; ++r) {
        const int m = 16 * mh1 + (l >> 4) * 4 + r;        // D-layout: col=lane&15, row=(lane>>4)*4+r
        float v = hacc[j][r] + b1v;
        float gl = 0.5f * v * (1.0f + erff(v * 0.70710678118654752f));
        gl *= routes_lds[m];
        const int sp = (flocal >> 3) ^ (m & 7);
        *(_Float16*)(hs + m * 128 + sp * 16 + (flocal & 7) * 2) = (_Float16)gl;
      }
    }
    asm volatile("s_waitcnt lgkmcnt(0)" ::: "memory");    // hs writes done before next barrier

    // ---- GEMM2: chunks 4..7 (w2 [128d][64f]) ----
#pragma unroll
    for (int c = 0; c < 4; ++c) {
      asm volatile("s_waitcnt vmcnt(4)" ::: "memory");    // chunk 4+c landed
      __builtin_amdgcn_s_barrier();                       // also publishes hs (c==0)
      const unsigned char* bb = ring[c & 3];              // chunk 4+c -> slot (4+c)&3 = c
      __builtin_amdgcn_s_setprio(1);
#pragma unroll
      for (int ks2 = 0; ks2 < 2; ++ks2) {
        half8 a2[2];
#pragma unroll
        for (int mi = 0; mi < 2; ++mi) {
          const int am2 = 32 * mh2 + 16 * mi + (l & 15);
          const int g2  = ks2 * 4 + (l >> 4);
          a2[mi] = *(const half8*)(hs + am2 * 128 + ((g2 ^ (am2 & 7))) * 16);
        }
#pragma unroll
        for (int jn = 0; jn < 2; ++jn) {
          const int dr = dq * 32 + jn * 16 + (l & 15);
          const int g  = ks2 * 4 + (l >> 4);
          half8 b = *(const half8*)(bb + dr * 128 + ((g ^ (dr & 7))) * 16);
          acc[0][c * 2 + jn] = __builtin_amdgcn_mfma_f32_16x16x32_f16(a2[0], b, acc[0][c * 2 + jn], 0, 0, 0);
          acc[1][c * 2 + jn] = __builtin_amdgcn_mfma_f32_16x16x32_f16(a2[1], b, acc[1][c * 2 + jn], 0, 0, 0);
        }
      }
      __builtin_amdgcn_s_setprio(0);
      const int j2 = c + 7;                               // chunks 7,8,9,10 (8+: next fc w1)
      if (j2 < 8) stage_chunk(w1t, w2t, e, f0,  j2,     ring[j2 & 3], w, l);
      else        stage_chunk(w1t, w2t, e, f0n, j2 - 8, ring[j2 & 3], w, l);
    }
  }

  // ---- epilogue: += route*b2, atomic-accumulate across experts ----
#pragma unroll
  for (int mi = 0; mi < 2; ++mi)
#pragma unroll
    for (int c = 0; c < 4; ++c)
#pragma unroll
      for (int jn = 0; jn < 2; ++jn) {
        const int dcol = c * 128 + dq * 32 + jn * 16 + (l & 15);
        float b2v = b2[(size_t)e * D_MODEL + dcol];
#pragma unroll
        for (int r = 0; r < 4; ++r) {
          const int m = 32 * mh2 + 16 * mi + (l >> 4) * 4 + r;
          float val = acc[mi][c * 2 + jn][r] + routes_lds[m] * b2v;
          unsafeAtomicAdd(out + (size_t)(m0 + m) * D_MODEL + dcol, val);
        }
      }
}

extern "C" void kernel_launch(void* const* d_in, const int* in_sizes, int n_in,
                              void* d_out, int out_size, void* d_ws, size_t ws_size,
                              hipStream_t stream) {
  (void)in_sizes; (void)n_in; (void)out_size; (void)ws_size;
  const float* x  = (const float*)d_in[0];
  const float* w1 = (const float*)d_in[1];
  const float* b1 = (const float*)d_in[2];
  const float* w2 = (const float*)d_in[3];
  const float* b2 = (const float*)d_in[4];
  const float* wr = (const float*)d_in[5];
  const float* br = (const float*)d_in[6];
  float* out   = (float*)d_out;
  float* route = out + (size_t)N_TOK * D_MODEL;   // output 1 lives in d_out tail

  char* ws = (char*)d_ws;
  _Float16* xb  = (_Float16*)ws;                                           // 8 MiB
  _Float16* w1t = (_Float16*)(ws + (size_t)N_TOK * D_MODEL * 2);           // +16 MiB  [E][F][D]
  _Float16* w2t = (_Float16*)(ws + (size_t)N_TOK * D_MODEL * 2
                                 + (size_t)N_EXP * D_FF * D_MODEL * 2);    // +16 MiB  [E][D][F]

  hipMemsetAsync(out, 0, (size_t)N_TOK * D_MODEL * sizeof(float), stream);
  cvt_x_kernel<<<(N_TOK * D_MODEL / 8) / 256, 256, 0, stream>>>(x, xb);
  transpose_cvt_kernel<<<dim3(D_FF / 32, D_MODEL / 32, N_EXP), 256, 0, stream>>>(w1, w1t, D_MODEL, D_FF);
  transpose_cvt_kernel<<<dim3(D_MODEL / 32, D_FF / 32, N_EXP), 256, 0, stream>>>(w2, w2t, D_FF, D_MODEL);
  router_kernel<<<N_TOK / 4, 256, 0, stream>>>(x, wr, br, route);
  moe_main_kernel<<<dim3(N_TOK / BM, N_EXP), 512, 0, stream>>>(xb, w1t, w2t, b1, b2, route, out);
}

// Round 3
// 600.619 us; speedup vs baseline: 1.3679x; 1.0629x over previous
//
#include <hip/hip_runtime.h>
#include <math.h>

#define D_MODEL 512
#define D_FF    2048
#define N_EXP   8
#define N_TOK   8192
#define BM      64
#define BF      64

typedef _Float16 half8 __attribute__((ext_vector_type(8)));
typedef float    f32x4 __attribute__((ext_vector_type(4)));

__device__ __forceinline__ void gload_lds16(const void* g, void* lds) {
  __builtin_amdgcn_global_load_lds(
      (const __attribute__((address_space(1))) unsigned int*)g,
      (__attribute__((address_space(3))) unsigned int*)lds, 16, 0, 0);
}

// ---------------- x -> fp16 ----------------
__global__ void cvt_x_kernel(const float* __restrict__ x, _Float16* __restrict__ xb) {
  int i = blockIdx.x * blockDim.x + threadIdx.x;   // 8 elems per thread
  const float4* xp = (const float4*)x + (size_t)i * 2;
  float4 v0 = xp[0], v1 = xp[1];
  half8 o;
  o[0] = (_Float16)v0.x; o[1] = (_Float16)v0.y; o[2] = (_Float16)v0.z; o[3] = (_Float16)v0.w;
  o[4] = (_Float16)v1.x; o[5] = (_Float16)v1.y; o[6] = (_Float16)v1.z; o[7] = (_Float16)v1.w;
  ((half8*)xb)[i] = o;
}

// ---------------- [E][R][C] f32 -> [E][C][R] f16 ----------------
__global__ void transpose_cvt_kernel(const float* __restrict__ in, _Float16* __restrict__ out,
                                     int R, int C) {
  __shared__ float t[32][33];
  int e = blockIdx.z, rb = blockIdx.y, cb = blockIdx.x;
  int tx = threadIdx.x & 31, ty = threadIdx.x >> 5;
  const float* src = in + ((size_t)e * R + rb * 32) * C + cb * 32;
#pragma unroll
  for (int i = 0; i < 32; i += 8) t[ty + i][tx] = src[(size_t)(ty + i) * C + tx];
  __syncthreads();
  _Float16* dst = out + ((size_t)e * C + cb * 32) * R + rb * 32;
#pragma unroll
  for (int i = 0; i < 32; i += 8) dst[(size_t)(ty + i) * R + tx] = (_Float16)t[tx][ty + i];
}

// ---------------- router: softmax(x @ wr + br) ----------------
__global__ void router_kernel(const float* __restrict__ x, const float* __restrict__ wr,
                              const float* __restrict__ br, float* __restrict__ route) {
  int t = (blockIdx.x * blockDim.x + threadIdx.x) >> 6;   // one wave per token
  int lane = threadIdx.x & 63;
  const float4* xp = (const float4*)(x + (size_t)t * D_MODEL) + lane * 2;
  float4 xv0 = xp[0], xv1 = xp[1];
  float xv[8] = {xv0.x, xv0.y, xv0.z, xv0.w, xv1.x, xv1.y, xv1.z, xv1.w};
  float acc[8] = {0, 0, 0, 0, 0, 0, 0, 0};
  int d0 = lane * 8;
#pragma unroll
  for (int i = 0; i < 8; ++i) {
    const float4* wp = (const float4*)(wr + (size_t)(d0 + i) * N_EXP);
    float4 w0 = wp[0], w1v = wp[1];
    acc[0] += xv[i] * w0.x;  acc[1] += xv[i] * w0.y;
    acc[2] += xv[i] * w0.z;  acc[3] += xv[i] * w0.w;
    acc[4] += xv[i] * w1v.x; acc[5] += xv[i] * w1v.y;
    acc[6] += xv[i] * w1v.z; acc[7] += xv[i] * w1v.w;
  }
#pragma unroll
  for (int off = 32; off > 0; off >>= 1)
#pragma unroll
    for (int e2 = 0; e2 < 8; ++e2) acc[e2] += __shfl_xor(acc[e2], off);
  float mx = -1e30f;
#pragma unroll
  for (int e2 = 0; e2 < 8; ++e2) { acc[e2] += br[e2]; mx = fmaxf(mx, acc[e2]); }
  float s = 0.f;
#pragma unroll
  for (int e2 = 0; e2 < 8; ++e2) { acc[e2] = expf(acc[e2] - mx); s += acc[e2]; }
  float inv = 1.f / s;
  if (lane < 8) route[(size_t)t * N_EXP + lane] = acc[lane] * inv;
}

// ---------------- staging: one 16KB ring slot ----------------
// idx 0..3: w1 chunk [64f][128k], k8 = idx (row = 256B, 16 slots, XOR-swizzled)
// idx 4..7: w2 slot [256d][32f]:  ks = (idx-4)>>1, dhalf = (idx-4)&1
//           (row = 64B; 3-bit swizzle over 128B row-pairs: t' = t ^ ((dr>>1)&7))
__device__ __forceinline__ void stage_slot(const _Float16* __restrict__ w1t,
                                           const _Float16* __restrict__ w2t,
                                           int e, int f0, int idx, void* ringbase,
                                           int w, int l) {
  char* slot = (char*)ringbase + idx * 16384;
  if (idx < 4) {
    const int k0 = idx * 128;
#pragma unroll
    for (int i = 0; i < 2; ++i) {
      int fr = i * 32 + w * 4 + (l >> 4);
      int s  = l & 15;
      int sw = (s & 8) | ((s ^ (fr & 7)) & 7);
      gload_lds16(w1t + ((size_t)e * D_FF + f0 + fr) * D_MODEL + k0 + sw * 8,
                  slot + (i * 32 + w * 4) * 256);
    }
  } else {
    const int ks = (idx - 4) >> 1, dh = (idx - 4) & 1;
    const int fbase = f0 + ks * 32;
#pragma unroll
    for (int i = 0; i < 2; ++i) {
      int n  = (w * 2 + i) * 64 + l;     // linear 16B index in slot
      int h  = n >> 3;
      int t  = (n & 7) ^ (h & 7);        // inverse of read swizzle (XOR involution)
      int dr = h * 2 + (t >> 2);
      int s  = t & 3;
      gload_lds16(w2t + ((size_t)e * D_MODEL + dh * 256 + dr) * D_FF + fbase + s * 8,
                  slot + (w * 2 + i) * 1024);
    }
  }
}

// ---------------- fused MoE main ----------------
// grid (128, 2), 512 threads. Block: 64-token m-tile x 4 experts (xfrag reuse,
// 2-way output atomics). Per (expert,fc): 6 phases over an 8-slot/16KB ring,
// stage-ahead 6 slots, waits vmcnt(10)/vmcnt(8) — never drained in-loop (T4).
// GEMM1: m-split 2 (xfrag[2][16] in regs) x f-split 4 -> B read 2x/CU.
// GEMM2: d-split 8 (64 cols/wave) -> B read 1x/CU; A (hs) shared across 4 d-tiles.
__global__ __launch_bounds__(512, 2)
void moe_main_kernel(const _Float16* __restrict__ xb, const _Float16* __restrict__ w1t,
                     const _Float16* __restrict__ w2t, const float* __restrict__ b1,
                     const float* __restrict__ b2, const float* __restrict__ route,
                     float* __restrict__ out) {
  __shared__ __align__(16) unsigned char ring[8][16384];   // 128 KB
  __shared__ __align__(16) unsigned char hs[BM * BF * 2];  // 8 KB
  __shared__ float routes_lds[4][BM];                      // 1 KB

  const int tid = threadIdx.x;
  const int l   = tid & 63;
  const int w   = tid >> 6;
  const int eb  = 4 * blockIdx.y;
  const int m0  = blockIdx.x * BM;

  const int mh1 = w & 1;     // GEMM1: 2 m-groups of 32 rows
  const int fq  = w >> 1;    // GEMM1: 4 f-groups of 16 cols
  const int dq  = w;         // GEMM2: 8 d-groups of 64 cols

  if (tid < 4 * BM)
    routes_lds[tid >> 6][tid & 63] = route[(size_t)(m0 + (tid & 63)) * N_EXP + eb + (tid >> 6)];
  asm volatile("s_waitcnt lgkmcnt(0)" ::: "memory");

  // x A-fragments in registers: 2 m-frags x 16 k-steps (128 VGPR), reused by all 4 experts
  half8 xfrag[2][16];
#pragma unroll
  for (int mi = 0; mi < 2; ++mi) {
    const _Float16* xrow = xb + (size_t)(m0 + 32 * mh1 + 16 * mi + (l & 15)) * D_MODEL + (l >> 4) * 8;
#pragma unroll
    for (int ks = 0; ks < 16; ++ks)
      xfrag[mi][ks] = *(const half8*)(xrow + ks * 32);
  }

  f32x4 acc[4][4];
#pragma unroll
  for (int a = 0; a < 4; ++a)
#pragma unroll
    for (int b = 0; b < 4; ++b) acc[a][b] = (f32x4){0.f, 0.f, 0.f, 0.f};

  // prologue: stage slots 0..5 of (eb, fc=0)
#pragma unroll
  for (int s = 0; s < 6; ++s) stage_slot(w1t, w2t, eb, 0, s, ring, w, l);

#pragma unroll 1
  for (int ei = 0; ei < 4; ++ei) {
    const int e = eb + ei;
#pragma unroll 1
    for (int fc = 0; fc < 32; ++fc) {
      const int f0 = fc * BF;
      int f0N = f0 + BF, eN = e;
      if (f0N == D_FF) { f0N = 0; eN = (ei < 3) ? e + 1 : eb; }  // end-clamp: harmless extra loads

      const int flocal = 16 * fq + (l & 15);
      float b1v = b1[(size_t)e * D_FF + f0 + flocal];   // prefetched; compiler wait is slack-free

      f32x4 hacc[2];
      hacc[0] = (f32x4){0.f, 0.f, 0.f, 0.f};
      hacc[1] = (f32x4){0.f, 0.f, 0.f, 0.f};

      // ---- GEMM1: 4 phases, slot k8 = ring[0..3] ----
#pragma unroll
      for (int k8 = 0; k8 < 4; ++k8) {
        asm volatile("s_waitcnt vmcnt(10)" ::: "memory");
        __builtin_amdgcn_s_barrier();
        const unsigned char* bb = ring[k8];
        __builtin_amdgcn_s_setprio(1);
#pragma unroll
        for (int kh = 0; kh < 4; ++kh) {
          const int g  = kh * 4 + (l >> 4);
          const int sw = (g & 8) | ((g ^ (flocal & 7)) & 7);
          half8 b = *(const half8*)(bb + flocal * 256 + sw * 16);
          hacc[0] = __builtin_amdgcn_mfma_f32_16x16x32_f16(xfrag[0][k8 * 4 + kh], b, hacc[0], 0, 0, 0);
          hacc[1] = __builtin_amdgcn_mfma_f32_16x16x32_f16(xfrag[1][k8 * 4 + kh], b, hacc[1], 0, 0, 0);
        }
        __builtin_amdgcn_s_setprio(0);
        if      (k8 == 0) stage_slot(w1t, w2t, e,  f0,  6, ring, w, l);
        else if (k8 == 1) stage_slot(w1t, w2t, e,  f0,  7, ring, w, l);
        else if (k8 == 2) stage_slot(w1t, w2t, eN, f0N, 0, ring, w, l);
        else              stage_slot(w1t, w2t, eN, f0N, 1, ring, w, l);
      }

      // ---- bias + exact gelu + route-scale -> hs ----
#pragma unroll
      for (int mi = 0; mi < 2; ++mi) {
#pragma unroll
        for (int r = 0; r < 4; ++r) {
          const int m = 32 * mh1 + 16 * mi + (l >> 4) * 4 + r;
          float v = hacc[mi][r] + b1v;
          float gl = 0.5f * v * (1.0f + erff(v * 0.70710678118654752f));
          gl *= routes_lds[ei][m];
          const int sp = (flocal >> 3) ^ (m & 7);
          *(_Float16*)(hs + m * 128 + sp * 16 + (flocal & 7) * 2) = (_Float16)gl;
        }
      }
      asm volatile("s_waitcnt lgkmcnt(0)" ::: "memory");

      // ---- GEMM2: 2 phases (ks), slots ring[4+2ks + dhalf] ----
#pragma unroll
      for (int ks = 0; ks < 2; ++ks) {
        asm volatile("s_waitcnt vmcnt(8)" ::: "memory");
        __builtin_amdgcn_s_barrier();
        const unsigned char* bslot = ring[4 + 2 * ks + (dq >> 2)];
        __builtin_amdgcn_s_setprio(1);
        half8 a2[4];
#pragma unroll
        for (int mi2 = 0; mi2 < 4; ++mi2) {
          const int am2 = 16 * mi2 + (l & 15);
          const int g2  = ks * 4 + (l >> 4);
          a2[mi2] = *(const half8*)(hs + am2 * 128 + ((g2 ^ (am2 & 7)) & 7) * 16);
        }
#pragma unroll
        for (int jn = 0; jn < 4; ++jn) {
          const int drl = 64 * (dq & 3) + 16 * jn + (l & 15);
          const int t   = ((drl & 1) << 2) | (l >> 4);
          const int tp  = t ^ ((drl >> 1) & 7);
          half8 b = *(const half8*)(bslot + (drl >> 1) * 128 + tp * 16);
#pragma unroll
          for (int mi2 = 0; mi2 < 4; ++mi2)
            acc[mi2][jn] = __builtin_amdgcn_mfma_f32_16x16x32_f16(a2[mi2], b, acc[mi2][jn], 0, 0, 0);
        }
        __builtin_amdgcn_s_setprio(0);
        stage_slot(w1t, w2t, eN, f0N, 2 + ks * 2, ring, w, l);
        stage_slot(w1t, w2t, eN, f0N, 3 + ks * 2, ring, w, l);
      }
    }

    // ---- expert end: fold route*b2 into acc ----
#pragma unroll
    for (int jn = 0; jn < 4; ++jn) {
      const int dcol = 64 * dq + 16 * jn + (l & 15);
      float b2v = b2[(size_t)e * D_MODEL + dcol];
#pragma unroll
      for (int mi2 = 0; mi2 < 4; ++mi2)
#pragma unroll
        for (int r = 0; r < 4; ++r) {
          const int m = 16 * mi2 + (l >> 4) * 4 + r;
          acc[mi2][jn][r] += routes_lds[ei][m] * b2v;
        }
    }
  }

  asm volatile("s_waitcnt vmcnt(0)" ::: "memory");   // drain clamp-staged tail before exit

  // ---- epilogue: 2-way atomic accumulate across expert-group blocks ----
#pragma unroll
  for (int mi2 = 0; mi2 < 4; ++mi2)
#pragma unroll
    for (int jn = 0; jn < 4; ++jn) {
      const int dcol = 64 * dq + 16 * jn + (l & 15);
#pragma unroll
      for (int r = 0; r < 4; ++r) {
        const int m = 16 * mi2 + (l >> 4) * 4 + r;
        unsafeAtomicAdd(out + (size_t)(m0 + m) * D_MODEL + dcol, acc[mi2][jn][r]);
      }
    }
}

extern "C" void kernel_launch(void* const* d_in, const int* in_sizes, int n_in,
                              void* d_out, int out_size, void* d_ws, size_t ws_size,
                              hipStream_t stream) {
  (void)in_sizes; (void)n_in; (void)out_size; (void)ws_size;
  const float* x  = (const float*)d_in[0];
  const float* w1 = (const float*)d_in[1];
  const float* b1 = (const float*)d_in[2];
  const float* w2 = (const float*)d_in[3];
  const float* b2 = (const float*)d_in[4];
  const float* wr = (const float*)d_in[5];
  const float* br = (const float*)d_in[6];
  float* out   = (float*)d_out;
  float* route = out + (size_t)N_TOK * D_MODEL;   // output 1 lives in d_out tail

  char* ws = (char*)d_ws;
  _Float16* xb  = (_Float16*)ws;                                           // 8 MiB
  _Float16* w1t = (_Float16*)(ws + (size_t)N_TOK * D_MODEL * 2);           // +16 MiB  [E][F][D]
  _Float16* w2t = (_Float16*)(ws + (size_t)N_TOK * D_MODEL * 2
                                 + (size_t)N_EXP * D_FF * D_MODEL * 2);    // +16 MiB  [E][D][F]

  hipMemsetAsync(out, 0, (size_t)N_TOK * D_MODEL * sizeof(float), stream);
  cvt_x_kernel<<<(N_TOK * D_MODEL / 8) / 256, 256, 0, stream>>>(x, xb);
  transpose_cvt_kernel<<<dim3(D_FF / 32, D_MODEL / 32, N_EXP), 256, 0, stream>>>(w1, w1t, D_MODEL, D_FF);
  transpose_cvt_kernel<<<dim3(D_MODEL / 32, D_FF / 32, N_EXP), 256, 0, stream>>>(w2, w2t, D_FF, D_MODEL);
  router_kernel<<<N_TOK / 4, 256, 0, stream>>>(x, wr, br, route);
  moe_main_kernel<<<dim3(N_TOK / BM, 2), 512, 0, stream>>>(xb, w1t, w2t, b1, b2, route, out);
}